// Round 4
// baseline (374.727 us; speedup 1.0000x reference)
//
#include <hip/hip_runtime.h>
#include <hip/hip_bf16.h>

// ---------- types ----------
typedef __attribute__((ext_vector_type(8))) short bf16x8;   // 8 bf16 in 4 VGPRs
typedef __attribute__((ext_vector_type(4))) float f32x4;

__device__ inline unsigned short f2b(float x) {
  __hip_bfloat16 b = __float2bfloat16(x);
  return *reinterpret_cast<unsigned short*>(&b);
}
__device__ inline float b2f(unsigned short u) {
  return __bfloat162float(*reinterpret_cast<const __hip_bfloat16*>(&u));
}

#define GAS(p) ((const __attribute__((address_space(1))) void*)(p))
#define LAS(p) ((__attribute__((address_space(3))) void*)(p))

// ---------- elementwise cast f32 -> bf16 (vectorized) ----------
__global__ __launch_bounds__(256) void cast_f32_bf16(const float* __restrict__ X,
                                                     unsigned short* __restrict__ Y, int n4) {
  int i = blockIdx.x * 256 + threadIdx.x;
  if (i < n4) {
    float4 v = reinterpret_cast<const float4*>(X)[i];
    ushort4 o;
    o.x = f2b(v.x); o.y = f2b(v.y); o.z = f2b(v.z); o.w = f2b(v.w);
    reinterpret_cast<ushort4*>(Y)[i] = o;
  }
}

// ---------- transpose + cast: W [K][N] f32 -> Wt [N][K] bf16 ----------
__global__ __launch_bounds__(256) void tcast(const float* __restrict__ W,
                                             unsigned short* __restrict__ Wt, int K, int N) {
  __shared__ float tile[32][33];
  int n0 = blockIdx.x * 32, k0 = blockIdx.y * 32;
  int tx = threadIdx.x & 31, ty = threadIdx.x >> 5;  // 32 x 8
#pragma unroll
  for (int i = 0; i < 32; i += 8)
    tile[ty + i][tx] = W[(size_t)(k0 + ty + i) * N + n0 + tx];
  __syncthreads();
#pragma unroll
  for (int i = 0; i < 32; i += 8)
    Wt[(size_t)(n0 + ty + i) * K + k0 + tx] = f2b(tile[tx][ty + i]);
}

// ---------- V transpose+cast: qkvF[:,4096+c] f32 -> Vt[c][t] bf16 ----------
__global__ __launch_bounds__(256) void vtrans(const float* __restrict__ qkv,
                                              unsigned short* __restrict__ Vt) {
  __shared__ unsigned short tile[32][33];
  int c0 = blockIdx.x * 32;  // hd dim
  int t0 = blockIdx.y * 32;  // token dim
  int tx = threadIdx.x & 31, ty = threadIdx.x >> 5;  // 32 x 8
#pragma unroll
  for (int i = 0; i < 32; i += 8)
    tile[ty + i][tx] = f2b(qkv[(size_t)(t0 + ty + i) * 6144 + 4096 + c0 + tx]);
  __syncthreads();
#pragma unroll
  for (int i = 0; i < 32; i += 8)
    Vt[(size_t)(c0 + ty + i) * 2048 + t0 + tx] = tile[tx][ty + i];
}

// ---------- bf16 MFMA GEMM: C[M][N] = A[M][K] * Bt[N][K]^T, fp32 out ----------
// 128x128 tile, BK=32, 256 threads (4 waves, 2x2 wave grid, each wave 64x64).
__global__ __launch_bounds__(256) void gemm_bt(const unsigned short* __restrict__ A,
                                               const unsigned short* __restrict__ Bt,
                                               float* __restrict__ C, int M, int N, int K) {
  __shared__ unsigned short As[128 * 32];
  __shared__ unsigned short Bs[128 * 32];
  const int tid = threadIdx.x;
  const int w = tid >> 6, l = tid & 63;
  const int lr = l & 15, lg = l >> 4;
  const int wm = (w >> 1) << 6, wn = (w & 1) << 6;
  const size_t bm = (size_t)blockIdx.y * 128, bn = (size_t)blockIdx.x * 128;

  const int srow = tid >> 2;
  const int scol = (tid & 3) << 3;
  const unsigned short* Ag = A + (bm + srow) * (size_t)K + scol;
  const unsigned short* Bg = Bt + (bn + srow) * (size_t)K + scol;
  unsigned short* Al = As + w * 512;   // wave-uniform LDS base; HW adds lane*16B
  unsigned short* Bl = Bs + w * 512;

  f32x4 acc[4][4] = {};

  for (int k0 = 0; k0 < K; k0 += 32) {
    __syncthreads();
    __builtin_amdgcn_global_load_lds(GAS(Ag + k0), LAS(Al), 16, 0, 0);
    __builtin_amdgcn_global_load_lds(GAS(Ag + (size_t)64 * K + k0), LAS(Al + 2048), 16, 0, 0);
    __builtin_amdgcn_global_load_lds(GAS(Bg + k0), LAS(Bl), 16, 0, 0);
    __builtin_amdgcn_global_load_lds(GAS(Bg + (size_t)64 * K + k0), LAS(Bl + 2048), 16, 0, 0);
    __syncthreads();

    bf16x8 af[4], bfr[4];
#pragma unroll
    for (int mi = 0; mi < 4; ++mi)
      af[mi] = *reinterpret_cast<const bf16x8*>(&As[(wm + mi * 16 + lr) * 32 + lg * 8]);
#pragma unroll
    for (int ni = 0; ni < 4; ++ni)
      bfr[ni] = *reinterpret_cast<const bf16x8*>(&Bs[(wn + ni * 16 + lr) * 32 + lg * 8]);
#pragma unroll
    for (int mi = 0; mi < 4; ++mi)
#pragma unroll
      for (int ni = 0; ni < 4; ++ni)
        acc[mi][ni] = __builtin_amdgcn_mfma_f32_16x16x32_bf16(af[mi], bfr[ni], acc[mi][ni], 0, 0, 0);
  }

#pragma unroll
  for (int mi = 0; mi < 4; ++mi)
#pragma unroll
    for (int ni = 0; ni < 4; ++ni)
#pragma unroll
      for (int r = 0; r < 4; ++r) {
        size_t row = bm + wm + mi * 16 + lg * 4 + r;
        size_t col = bn + wn + ni * 16 + lr;
        C[row * N + col] = acc[mi][ni][r];
      }
}

// ---------- fused RMSNorm (over 2048) + RoPE, write bf16 q/k ----------
// Q is pre-scaled by softmax_scale * log2(e) so attention works in base-2.
__global__ __launch_bounds__(256) void rms_rope(const float* __restrict__ qkv,
                                                const int* __restrict__ pos,
                                                const float* __restrict__ qw,
                                                const float* __restrict__ kw,
                                                unsigned short* __restrict__ qb,
                                                unsigned short* __restrict__ kb) {
  const int t = blockIdx.x;
  const float* row = qkv + (size_t)t * 6144;
  __shared__ float redq[4], redk[4];
  __shared__ float cs[64], sn[64];
  const int tid = threadIdx.x, w = tid >> 6, l = tid & 63;

  float sq = 0.f, sk = 0.f;
#pragma unroll
  for (int i = 0; i < 8; ++i) {
    float a = row[tid + i * 256]; sq += a * a;
    float b = row[2048 + tid + i * 256]; sk += b * b;
  }
#pragma unroll
  for (int m = 32; m >= 1; m >>= 1) { sq += __shfl_xor(sq, m, 64); sk += __shfl_xor(sk, m, 64); }
  if (l == 0) { redq[w] = sq; redk[w] = sk; }
  if (tid < 64) {
    float fr = exp2f(-(float)tid * 0.31143075889569016f);  // theta^(-j/64)
    float ang = (float)pos[t] * fr;
    cs[tid] = cosf(ang);
    sn[tid] = sinf(ang);
  }
  __syncthreads();
  float rq = rsqrtf((redq[0] + redq[1] + redq[2] + redq[3]) * (1.f / 2048.f) + 1e-5f);
  float rk = rsqrtf((redk[0] + redk[1] + redk[2] + redk[3]) * (1.f / 2048.f) + 1e-5f);
  // fold softmax scale (1/sqrt(128)) * log2(e) into Q
  const float rqs = rq * 0.12753102543609887f;

  unsigned short* qo = qb + (size_t)t * 2048;
  unsigned short* ko = kb + (size_t)t * 2048;
#pragma unroll
  for (int pp = 0; pp < 4; ++pp) {
    int pr = tid + pp * 256;  // pair index 0..1023
    int h = pr >> 6, j = pr & 63;
    int b0 = h * 128 + j;
    float c = cs[j], s = sn[j];
    float x1 = row[b0] * rqs * qw[b0];
    float x2 = row[b0 + 64] * rqs * qw[b0 + 64];
    qo[b0]      = f2b(x1 * c - x2 * s);
    qo[b0 + 64] = f2b(x2 * c + x1 * s);
    float y1 = row[2048 + b0] * rk * kw[b0];
    float y2 = row[2048 + b0 + 64] * rk * kw[b0 + 64];
    ko[b0]      = f2b(y1 * c - y2 * s);
    ko[b0 + 64] = f2b(y2 * c + y1 * s);
  }
}

// ---------- attention helpers ----------
__device__ __forceinline__ void stage_kv(const unsigned short* __restrict__ kb_h,
                                         const unsigned short* __restrict__ vt_h,
                                         int k0, int w, int l,
                                         unsigned short* Ks, unsigned short* Vs) {
  // K: [64][128] swizzled 16B chunks (linear dest + inverse-swz source — rule #21)
  const int r0 = l >> 4, cph = l & 15;
#pragma unroll
  for (int rb = 0; rb < 16; rb += 4) {
    int row = w * 16 + rb + r0;
    int clog = (cph & 8) | ((cph & 7) ^ (row & 7));
    const unsigned short* src = kb_h + (size_t)(k0 + row) * 2048 + clog * 8;
    __builtin_amdgcn_global_load_lds(GAS(src), LAS((char*)Ks + (w * 16 + rb) * 256), 16, 0, 0);
  }
  // V^T: [128][64] swizzled 16B chunks
  const int r0v = l >> 3, cpv = l & 7;
#pragma unroll
  for (int rb = 0; rb < 32; rb += 8) {
    int row = w * 32 + rb + r0v;
    int clog = cpv ^ (row & 7);
    const unsigned short* src = vt_h + (size_t)row * 2048 + k0 + clog * 8;
    __builtin_amdgcn_global_load_lds(GAS(src), LAS((char*)Vs + (w * 32 + rb) * 128), 16, 0, 0);
  }
}

template <bool MASKED>
__device__ __forceinline__ void attn_tile(int k0, int qrbase, int lr, int lg,
                                          const bf16x8 (&qf)[4],
                                          const unsigned short* __restrict__ Ks,
                                          const unsigned short* __restrict__ Vs,
                                          unsigned short* __restrict__ PsW,
                                          f32x4 (&oacc)[8], float (&mrow)[4], float (&lrow)[4]) {
  f32x4 s[4] = {};
  __builtin_amdgcn_s_setprio(1);
#pragma unroll
  for (int kc = 0; kc < 4; ++kc)
#pragma unroll
    for (int cg = 0; cg < 4; ++cg) {
      int key = cg * 16 + lr;
      int c = 4 * kc + lg;
      int cswz = (c & 8) | ((c & 7) ^ (key & 7));
      bf16x8 kf = *reinterpret_cast<const bf16x8*>(&Ks[key * 128 + cswz * 8]);
      s[cg] = __builtin_amdgcn_mfma_f32_16x16x32_bf16(qf[kc], kf, s[cg], 0, 0, 0);
    }
  __builtin_amdgcn_s_setprio(0);

#pragma unroll
  for (int r = 0; r < 4; ++r) {
    const int qr = qrbase + lg * 4 + r;
    float p0 = s[0][r], p1 = s[1][r], p2 = s[2][r], p3 = s[3][r];
    if (MASKED) {
      if (k0 + lr > qr)      p0 = -1e30f;
      if (k0 + 16 + lr > qr) p1 = -1e30f;
      if (k0 + 32 + lr > qr) p2 = -1e30f;
      if (k0 + 48 + lr > qr) p3 = -1e30f;
    }
    float mx = fmaxf(fmaxf(p0, p1), fmaxf(p2, p3));
#pragma unroll
    for (int m = 8; m >= 1; m >>= 1) mx = fmaxf(mx, __shfl_xor(mx, m, 16));
    float mnew = fmaxf(mrow[r], mx);
    float corr = exp2f(mrow[r] - mnew);
    p0 = exp2f(p0 - mnew); p1 = exp2f(p1 - mnew);
    p2 = exp2f(p2 - mnew); p3 = exp2f(p3 - mnew);
    lrow[r] = lrow[r] * corr + ((p0 + p1) + (p2 + p3));  // per-lane partial; reduce at end
    mrow[r] = mnew;
#pragma unroll
    for (int ni = 0; ni < 8; ++ni) oacc[ni][r] *= corr;
    const int prow = (lg * 4 + r) * 72;
    PsW[prow + lr]      = f2b(p0);
    PsW[prow + 16 + lr] = f2b(p1);
    PsW[prow + 32 + lr] = f2b(p2);
    PsW[prow + 48 + lr] = f2b(p3);
  }

  __builtin_amdgcn_s_setprio(1);
#pragma unroll
  for (int ks = 0; ks < 2; ++ks) {
    bf16x8 pf = *reinterpret_cast<const bf16x8*>(&PsW[lr * 72 + ks * 32 + lg * 8]);
#pragma unroll
    for (int ni = 0; ni < 8; ++ni) {
      int d = ni * 16 + lr;
      int c = ks * 4 + lg;
      int cswz = c ^ (d & 7);
      bf16x8 vf = *reinterpret_cast<const bf16x8*>(&Vs[d * 64 + cswz * 8]);
      oacc[ni] = __builtin_amdgcn_mfma_f32_16x16x32_bf16(pf, vf, oacc[ni], 0, 0, 0);
    }
  }
  __builtin_amdgcn_s_setprio(0);
}

// ---------- causal flash attention, K-split partials ----------
// grid (32 qtiles, 16 heads, 8 splits of 256 keys), 256 thr (4 waves x 16 q-rows).
// KVBLK=64. Steady-state tiles are unmasked; exactly one diag tile masks.
// Partials compacted: unit u = h*144 + prefix(qt) + sp, prefix(qt)=(g+1)(2g+j).
__global__ __launch_bounds__(256) void attn_part(const unsigned short* __restrict__ qb,
                                                 const unsigned short* __restrict__ kb,
                                                 const unsigned short* __restrict__ vt,
                                                 unsigned short* __restrict__ Op,
                                                 float* __restrict__ ml) {
  __shared__ unsigned short Ks[64 * 128];
  __shared__ unsigned short Vs[128 * 64];
  __shared__ unsigned short Ps[4][16 * 72];
  const int qt = blockIdx.x, h = blockIdx.y, sp = blockIdx.z;
  const int q0 = qt * 64;
  const int kbeg = sp * 256;
  if (kbeg >= q0 + 64) return;
  const int tid = threadIdx.x, w = tid >> 6, l = tid & 63;
  const int lr = l & 15, lg = l >> 4;
  const int qrbase = q0 + w * 16;

  bf16x8 qf[4];
  {
    const unsigned short* qp = qb + (size_t)(qrbase + lr) * 2048 + h * 128;
#pragma unroll
    for (int kc = 0; kc < 4; ++kc)
      qf[kc] = *reinterpret_cast<const bf16x8*>(qp + kc * 32 + lg * 8);
  }
  f32x4 oacc[8] = {};
  float mrow[4], lrow[4];
#pragma unroll
  for (int r = 0; r < 4; ++r) { mrow[r] = -1e30f; lrow[r] = 0.f; }

  const unsigned short* kb_h = kb + h * 128;
  const unsigned short* vt_h = vt + (size_t)h * 128 * 2048;

  const int kstop_full = min(kbeg + 256, q0);
  for (int k0 = kbeg; k0 < kstop_full; k0 += 64) {
    __syncthreads();
    stage_kv(kb_h, vt_h, k0, w, l, Ks, Vs);
    __syncthreads();
    attn_tile<false>(k0, qrbase, lr, lg, qf, Ks, Vs, Ps[w], oacc, mrow, lrow);
  }
  if (q0 >= kbeg && q0 < kbeg + 256) {  // diagonal tile (only in split qt/4)
    __syncthreads();
    stage_kv(kb_h, vt_h, q0, w, l, Ks, Vs);
    __syncthreads();
    attn_tile<true>(q0, qrbase, lr, lg, qf, Ks, Vs, Ps[w], oacc, mrow, lrow);
  }

  // finalize l: cross-lane reduce over the 16 lanes sharing each row
#pragma unroll
  for (int r = 0; r < 4; ++r)
#pragma unroll
    for (int m = 8; m >= 1; m >>= 1) lrow[r] += __shfl_xor(lrow[r], m, 16);

  // epilogue: unnormalized partial O (bf16) + per-row m,l (compacted layout)
  const int g = qt >> 2, j = qt & 3;
  const size_t u = (size_t)h * 144 + (g + 1) * (2 * g + j) + sp;
  const size_t baserow = u * 64 + w * 16;
#pragma unroll
  for (int ni = 0; ni < 8; ++ni)
#pragma unroll
    for (int r = 0; r < 4; ++r)
      Op[(baserow + lg * 4 + r) * 128 + ni * 16 + lr] = f2b(oacc[ni][r]);
  if (lr == 0) {
#pragma unroll
    for (int r = 0; r < 4; ++r) {
      size_t mi = (baserow + lg * 4 + r) * 2;
      ml[mi] = mrow[r]; ml[mi + 1] = lrow[r];
    }
  }
}

// ---------- combine K-split partials (static indexing — rule #20) ----------
__global__ __launch_bounds__(256) void attn_combine(const unsigned short* __restrict__ Op,
                                                    const float* __restrict__ ml,
                                                    unsigned short* __restrict__ ob) {
  const int qt = blockIdx.x, h = blockIdx.y;
  const int q0 = qt * 64;
  const int g = qt >> 2, j = qt & 3;
  const int ns = g + 1;  // 1..8 valid splits
  const size_t ubase = (size_t)h * 144 + (g + 1) * (2 * g + j);
  const int t = threadIdx.x;
  const int row = t >> 2, dp = (t & 3) * 32;

  float m_s[8], l_s[8];
  float M = -1e30f;
#pragma unroll
  for (int s = 0; s < 8; ++s) {
    if (s < ns) {
      size_t mi = ((ubase + s) * 64 + row) * 2;
      m_s[s] = ml[mi]; l_s[s] = ml[mi + 1];
    } else { m_s[s] = -1e30f; l_s[s] = 0.f; }
    M = fmaxf(M, m_s[s]);
  }
  float L = 0.f, wgt[8];
#pragma unroll
  for (int s = 0; s < 8; ++s) { wgt[s] = exp2f(m_s[s] - M); L += l_s[s] * wgt[s]; }
  float invL = 1.f / L;

  float acc[32];
#pragma unroll
  for (int jj = 0; jj < 32; ++jj) acc[jj] = 0.f;
#pragma unroll
  for (int s = 0; s < 8; ++s) {
    if (s < ns) {
      const unsigned short* op = Op + ((ubase + s) * 64 + row) * 128 + dp;
      float wg = wgt[s] * invL;
#pragma unroll
      for (int jj = 0; jj < 32; jj += 8) {
        bf16x8 v = *reinterpret_cast<const bf16x8*>(op + jj);
#pragma unroll
        for (int e = 0; e < 8; ++e) acc[jj + e] += wg * b2f((unsigned short)v[e]);
      }
    }
  }
  unsigned short* o = ob + (size_t)(q0 + row) * 2048 + h * 128 + dp;
#pragma unroll
  for (int jj = 0; jj < 32; ++jj) o[jj] = f2b(acc[jj]);
}

// ---------- launch ----------
extern "C" void kernel_launch(void* const* d_in, const int* in_sizes, int n_in,
                              void* d_out, int out_size, void* d_ws, size_t ws_size,
                              hipStream_t stream) {
  const float* hs   = (const float*)d_in[0];
  const int*   pos  = (const int*)d_in[1];
  const float* wqkv = (const float*)d_in[2];
  const float* qnw  = (const float*)d_in[3];
  const float* knw  = (const float*)d_in[4];
  const float* wo   = (const float*)d_in[5];
  float* out = (float*)d_out;

  char* ws = (char*)d_ws;
  size_t off = 0;
  auto take = [&](size_t bytes) {
    char* p = ws + off;
    off = (off + bytes + 255) & ~(size_t)255;
    return p;
  };
  unsigned short* hidA  = (unsigned short*)take(2048ull * 2048 * 2);
  unsigned short* wqkvT = (unsigned short*)take(6144ull * 2048 * 2);
  unsigned short* woT   = (unsigned short*)take(2048ull * 2048 * 2);
  float*          qkvF  = (float*)take(2048ull * 6144 * 4);
  unsigned short* qbv   = (unsigned short*)take(2048ull * 2048 * 2);
  unsigned short* kbv   = (unsigned short*)take(2048ull * 2048 * 2);
  unsigned short* vtb   = (unsigned short*)take(2048ull * 2048 * 2);
  unsigned short* attnb = (unsigned short*)take(2048ull * 2048 * 2);
  // aliases over qkvF (dead after rms_rope + vtrans):
  // Opart: 16 heads * 144 units * 64 rows * 128 d * 2B = 37.75 MiB
  unsigned short* Opart = (unsigned short*)qkvF;
  float*          mlb   = (float*)((char*)qkvF + 40ull * 1024 * 1024);  // 1.2 MiB, fits <48 MiB

  cast_f32_bf16<<<4096, 256, 0, stream>>>(hs, hidA, 1048576);
  tcast<<<dim3(192, 64), 256, 0, stream>>>(wqkv, wqkvT, 2048, 6144);
  tcast<<<dim3(64, 64), 256, 0, stream>>>(wo, woT, 2048, 2048);
  gemm_bt<<<dim3(48, 16), 256, 0, stream>>>(hidA, wqkvT, qkvF, 2048, 6144, 2048);
  rms_rope<<<2048, 256, 0, stream>>>(qkvF, pos, qnw, knw, qbv, kbv);
  vtrans<<<dim3(64, 64), 256, 0, stream>>>(qkvF, vtb);
  attn_part<<<dim3(32, 16, 8), 256, 0, stream>>>(qbv, kbv, vtb, Opart, mlb);
  attn_combine<<<dim3(32, 16), 256, 0, stream>>>(Opart, mlb, attnb);
  gemm_bt<<<dim3(16, 16), 256, 0, stream>>>(attnb, woT, out, 2048, 2048, 2048);
}

// Round 7
// 370.982 us; speedup vs baseline: 1.0101x; 1.0101x over previous
//
#include <hip/hip_runtime.h>
#include <hip/hip_bf16.h>

// ---------- types ----------
typedef __attribute__((ext_vector_type(8))) short bf16x8;   // 8 bf16 in 4 VGPRs
typedef __attribute__((ext_vector_type(4))) float f32x4;

__device__ inline unsigned short f2b(float x) {
  __hip_bfloat16 b = __float2bfloat16(x);
  return *reinterpret_cast<unsigned short*>(&b);
}
__device__ inline float b2f(unsigned short u) {
  return __bfloat162float(*reinterpret_cast<const __hip_bfloat16*>(&u));
}

#define GAS(p) ((const __attribute__((address_space(1))) void*)(p))
#define LAS(p) ((__attribute__((address_space(3))) void*)(p))

// ---------- elementwise cast f32 -> bf16 (vectorized) ----------
__global__ __launch_bounds__(256) void cast_f32_bf16(const float* __restrict__ X,
                                                     unsigned short* __restrict__ Y, int n4) {
  int i = blockIdx.x * 256 + threadIdx.x;
  if (i < n4) {
    float4 v = reinterpret_cast<const float4*>(X)[i];
    ushort4 o;
    o.x = f2b(v.x); o.y = f2b(v.y); o.z = f2b(v.z); o.w = f2b(v.w);
    reinterpret_cast<ushort4*>(Y)[i] = o;
  }
}

// ---------- transpose + cast: W [K][N] f32 -> Wt [N][K] bf16 ----------
__global__ __launch_bounds__(256) void tcast(const float* __restrict__ W,
                                             unsigned short* __restrict__ Wt, int K, int N) {
  __shared__ float tile[32][33];
  int n0 = blockIdx.x * 32, k0 = blockIdx.y * 32;
  int tx = threadIdx.x & 31, ty = threadIdx.x >> 5;  // 32 x 8
#pragma unroll
  for (int i = 0; i < 32; i += 8)
    tile[ty + i][tx] = W[(size_t)(k0 + ty + i) * N + n0 + tx];
  __syncthreads();
#pragma unroll
  for (int i = 0; i < 32; i += 8)
    Wt[(size_t)(n0 + ty + i) * K + k0 + tx] = f2b(tile[tx][ty + i]);
}

// ---------- V transpose+cast: qkvF[:,4096+c] f32 -> Vt[c][t] bf16 ----------
__global__ __launch_bounds__(256) void vtrans(const float* __restrict__ qkv,
                                              unsigned short* __restrict__ Vt) {
  __shared__ unsigned short tile[32][33];
  int c0 = blockIdx.x * 32;  // hd dim
  int t0 = blockIdx.y * 32;  // token dim
  int tx = threadIdx.x & 31, ty = threadIdx.x >> 5;  // 32 x 8
#pragma unroll
  for (int i = 0; i < 32; i += 8)
    tile[ty + i][tx] = f2b(qkv[(size_t)(t0 + ty + i) * 6144 + 4096 + c0 + tx]);
  __syncthreads();
#pragma unroll
  for (int i = 0; i < 32; i += 8)
    Vt[(size_t)(c0 + ty + i) * 2048 + t0 + tx] = tile[tx][ty + i];
}

// ---------- bf16 MFMA GEMM: C[M][N] = A[M][K] * Bt[N][K]^T, fp32 out ----------
// 128x128 tile, BK=32, 256 threads (4 waves, 2x2 wave grid, each wave 64x64).
__global__ __launch_bounds__(256) void gemm_bt(const unsigned short* __restrict__ A,
                                               const unsigned short* __restrict__ Bt,
                                               float* __restrict__ C, int M, int N, int K) {
  __shared__ unsigned short As[128 * 32];
  __shared__ unsigned short Bs[128 * 32];
  const int tid = threadIdx.x;
  const int w = tid >> 6, l = tid & 63;
  const int lr = l & 15, lg = l >> 4;
  const int wm = (w >> 1) << 6, wn = (w & 1) << 6;
  const size_t bm = (size_t)blockIdx.y * 128, bn = (size_t)blockIdx.x * 128;

  const int srow = tid >> 2;
  const int scol = (tid & 3) << 3;
  const unsigned short* Ag = A + (bm + srow) * (size_t)K + scol;
  const unsigned short* Bg = Bt + (bn + srow) * (size_t)K + scol;
  unsigned short* Al = As + w * 512;   // wave-uniform LDS base; HW adds lane*16B
  unsigned short* Bl = Bs + w * 512;

  f32x4 acc[4][4] = {};

  for (int k0 = 0; k0 < K; k0 += 32) {
    __syncthreads();
    __builtin_amdgcn_global_load_lds(GAS(Ag + k0), LAS(Al), 16, 0, 0);
    __builtin_amdgcn_global_load_lds(GAS(Ag + (size_t)64 * K + k0), LAS(Al + 2048), 16, 0, 0);
    __builtin_amdgcn_global_load_lds(GAS(Bg + k0), LAS(Bl), 16, 0, 0);
    __builtin_amdgcn_global_load_lds(GAS(Bg + (size_t)64 * K + k0), LAS(Bl + 2048), 16, 0, 0);
    __syncthreads();

    bf16x8 af[4], bfr[4];
#pragma unroll
    for (int mi = 0; mi < 4; ++mi)
      af[mi] = *reinterpret_cast<const bf16x8*>(&As[(wm + mi * 16 + lr) * 32 + lg * 8]);
#pragma unroll
    for (int ni = 0; ni < 4; ++ni)
      bfr[ni] = *reinterpret_cast<const bf16x8*>(&Bs[(wn + ni * 16 + lr) * 32 + lg * 8]);
#pragma unroll
    for (int mi = 0; mi < 4; ++mi)
#pragma unroll
      for (int ni = 0; ni < 4; ++ni)
        acc[mi][ni] = __builtin_amdgcn_mfma_f32_16x16x32_bf16(af[mi], bfr[ni], acc[mi][ni], 0, 0, 0);
  }

#pragma unroll
  for (int mi = 0; mi < 4; ++mi)
#pragma unroll
    for (int ni = 0; ni < 4; ++ni)
#pragma unroll
      for (int r = 0; r < 4; ++r) {
        size_t row = bm + wm + mi * 16 + lg * 4 + r;
        size_t col = bn + wn + ni * 16 + lr;
        C[row * N + col] = acc[mi][ni][r];
      }
}

// ---------- fused RMSNorm (over 2048) + RoPE, write bf16 q/k ----------
// Q is pre-scaled by softmax_scale * log2(e) so attention works in base-2.
__global__ __launch_bounds__(256) void rms_rope(const float* __restrict__ qkv,
                                                const int* __restrict__ pos,
                                                const float* __restrict__ qw,
                                                const float* __restrict__ kw,
                                                unsigned short* __restrict__ qb,
                                                unsigned short* __restrict__ kb) {
  const int t = blockIdx.x;
  const float* row = qkv + (size_t)t * 6144;
  __shared__ float redq[4], redk[4];
  __shared__ float cs[64], sn[64];
  const int tid = threadIdx.x, w = tid >> 6, l = tid & 63;

  float sq = 0.f, sk = 0.f;
#pragma unroll
  for (int i = 0; i < 8; ++i) {
    float a = row[tid + i * 256]; sq += a * a;
    float b = row[2048 + tid + i * 256]; sk += b * b;
  }
#pragma unroll
  for (int m = 32; m >= 1; m >>= 1) { sq += __shfl_xor(sq, m, 64); sk += __shfl_xor(sk, m, 64); }
  if (l == 0) { redq[w] = sq; redk[w] = sk; }
  if (tid < 64) {
    float fr = exp2f(-(float)tid * 0.31143075889569016f);  // theta^(-j/64)
    float ang = (float)pos[t] * fr;
    cs[tid] = cosf(ang);
    sn[tid] = sinf(ang);
  }
  __syncthreads();
  float rq = rsqrtf((redq[0] + redq[1] + redq[2] + redq[3]) * (1.f / 2048.f) + 1e-5f);
  float rk = rsqrtf((redk[0] + redk[1] + redk[2] + redk[3]) * (1.f / 2048.f) + 1e-5f);
  // fold softmax scale (1/sqrt(128)) * log2(e) into Q
  const float rqs = rq * 0.12753102543609887f;

  unsigned short* qo = qb + (size_t)t * 2048;
  unsigned short* ko = kb + (size_t)t * 2048;
#pragma unroll
  for (int pp = 0; pp < 4; ++pp) {
    int pr = tid + pp * 256;  // pair index 0..1023
    int h = pr >> 6, j = pr & 63;
    int b0 = h * 128 + j;
    float c = cs[j], s = sn[j];
    float x1 = row[b0] * rqs * qw[b0];
    float x2 = row[b0 + 64] * rqs * qw[b0 + 64];
    qo[b0]      = f2b(x1 * c - x2 * s);
    qo[b0 + 64] = f2b(x2 * c + x1 * s);
    float y1 = row[2048 + b0] * rk * kw[b0];
    float y2 = row[2048 + b0 + 64] * rk * kw[b0 + 64];
    ko[b0]      = f2b(y1 * c - y2 * s);
    ko[b0 + 64] = f2b(y2 * c + y1 * s);
  }
}

// ---------- attention helpers ----------
__device__ __forceinline__ void stage_kv(const unsigned short* __restrict__ kb_h,
                                         const unsigned short* __restrict__ vt_h,
                                         int k0, int w, int l,
                                         unsigned short* Ks, unsigned short* Vs) {
  // K: [64][128] swizzled 16B chunks (linear dest + inverse-swz source — rule #21)
  const int r0 = l >> 4, cph = l & 15;
#pragma unroll
  for (int rb = 0; rb < 16; rb += 4) {
    int row = w * 16 + rb + r0;
    int clog = (cph & 8) | ((cph & 7) ^ (row & 7));
    const unsigned short* src = kb_h + (size_t)(k0 + row) * 2048 + clog * 8;
    __builtin_amdgcn_global_load_lds(GAS(src), LAS((char*)Ks + (w * 16 + rb) * 256), 16, 0, 0);
  }
  // V^T: [128][64] swizzled 16B chunks
  const int r0v = l >> 3, cpv = l & 7;
#pragma unroll
  for (int rb = 0; rb < 32; rb += 8) {
    int row = w * 32 + rb + r0v;
    int clog = cpv ^ (row & 7);
    const unsigned short* src = vt_h + (size_t)row * 2048 + k0 + clog * 8;
    __builtin_amdgcn_global_load_lds(GAS(src), LAS((char*)Vs + (w * 32 + rb) * 128), 16, 0, 0);
  }
}

template <bool MASKED>
__device__ __forceinline__ void attn_tile(int k0, int qrbase, int lr, int lg,
                                          const bf16x8 (&qf)[4],
                                          const unsigned short* __restrict__ Ks,
                                          const unsigned short* __restrict__ Vs,
                                          unsigned short* __restrict__ PsW,
                                          f32x4 (&oacc)[8], float (&mrow)[4], float (&lrow)[4]) {
  f32x4 s[4] = {};
  __builtin_amdgcn_s_setprio(1);
#pragma unroll
  for (int kc = 0; kc < 4; ++kc)
#pragma unroll
    for (int cg = 0; cg < 4; ++cg) {
      int key = cg * 16 + lr;
      int c = 4 * kc + lg;
      int cswz = (c & 8) | ((c & 7) ^ (key & 7));
      bf16x8 kf = *reinterpret_cast<const bf16x8*>(&Ks[key * 128 + cswz * 8]);
      s[cg] = __builtin_amdgcn_mfma_f32_16x16x32_bf16(qf[kc], kf, s[cg], 0, 0, 0);
    }
  __builtin_amdgcn_s_setprio(0);

#pragma unroll
  for (int r = 0; r < 4; ++r) {
    const int qr = qrbase + lg * 4 + r;
    float p0 = s[0][r], p1 = s[1][r], p2 = s[2][r], p3 = s[3][r];
    if (MASKED) {
      if (k0 + lr > qr)      p0 = -1e30f;
      if (k0 + 16 + lr > qr) p1 = -1e30f;
      if (k0 + 32 + lr > qr) p2 = -1e30f;
      if (k0 + 48 + lr > qr) p3 = -1e30f;
    }
    float mx = fmaxf(fmaxf(p0, p1), fmaxf(p2, p3));
#pragma unroll
    for (int m = 8; m >= 1; m >>= 1) mx = fmaxf(mx, __shfl_xor(mx, m, 16));
    float mnew = fmaxf(mrow[r], mx);
    float corr = exp2f(mrow[r] - mnew);
    p0 = exp2f(p0 - mnew); p1 = exp2f(p1 - mnew);
    p2 = exp2f(p2 - mnew); p3 = exp2f(p3 - mnew);
    lrow[r] = lrow[r] * corr + ((p0 + p1) + (p2 + p3));  // per-lane partial; reduce at end
    mrow[r] = mnew;
#pragma unroll
    for (int ni = 0; ni < 8; ++ni) oacc[ni][r] *= corr;
    const int prow = (lg * 4 + r) * 72;
    PsW[prow + lr]      = f2b(p0);
    PsW[prow + 16 + lr] = f2b(p1);
    PsW[prow + 32 + lr] = f2b(p2);
    PsW[prow + 48 + lr] = f2b(p3);
  }

  __builtin_amdgcn_s_setprio(1);
#pragma unroll
  for (int ks = 0; ks < 2; ++ks) {
    bf16x8 pf = *reinterpret_cast<const bf16x8*>(&PsW[lr * 72 + ks * 32 + lg * 8]);
#pragma unroll
    for (int ni = 0; ni < 8; ++ni) {
      int d = ni * 16 + lr;
      int c = ks * 4 + lg;
      int cswz = c ^ (d & 7);
      bf16x8 vf = *reinterpret_cast<const bf16x8*>(&Vs[d * 64 + cswz * 8]);
      oacc[ni] = __builtin_amdgcn_mfma_f32_16x16x32_bf16(pf, vf, oacc[ni], 0, 0, 0);
    }
  }
  __builtin_amdgcn_s_setprio(0);
}

// ---------- causal flash attention, K-split partials, 2-phase pipelined ----------
// grid (32 qtiles, 16 heads, 4 splits of 512 keys), 256 thr (4 waves x 16 q-rows).
// KVBLK=64, double-buffered K/V staging: stage(t+1) issued BEFORE compute(t),
// one __syncthreads per tile (its vmcnt(0) drain lands after the compute).
__global__ __launch_bounds__(256) void attn_part(const unsigned short* __restrict__ qb,
                                                 const unsigned short* __restrict__ kb,
                                                 const unsigned short* __restrict__ vt,
                                                 unsigned short* __restrict__ Op,
                                                 float* __restrict__ ml) {
  __shared__ unsigned short Ks[2][64 * 128];
  __shared__ unsigned short Vs[2][128 * 64];
  __shared__ unsigned short Ps[4][16 * 72];
  const int qt = blockIdx.x, h = blockIdx.y, sp = blockIdx.z;
  const int q0 = qt * 64;
  const int kbeg = sp * 512;
  if (kbeg >= q0 + 64) return;
  const int kend = min(kbeg + 512, q0 + 64);
  const int nt = (kend - kbeg) >> 6;  // 1..8 tiles
  const int tid = threadIdx.x, w = tid >> 6, l = tid & 63;
  const int lr = l & 15, lg = l >> 4;
  const int qrbase = q0 + w * 16;

  const unsigned short* kb_h = kb + h * 128;
  const unsigned short* vt_h = vt + (size_t)h * 128 * 2048;

  // prologue: stage tile 0, load Q while it flies
  stage_kv(kb_h, vt_h, kbeg, w, l, Ks[0], Vs[0]);

  bf16x8 qf[4];
  {
    const unsigned short* qp = qb + (size_t)(qrbase + lr) * 2048 + h * 128;
#pragma unroll
    for (int kc = 0; kc < 4; ++kc)
      qf[kc] = *reinterpret_cast<const bf16x8*>(qp + kc * 32 + lg * 8);
  }
  f32x4 oacc[8] = {};
  float mrow[4], lrow[4];
#pragma unroll
  for (int r = 0; r < 4; ++r) { mrow[r] = -1e30f; lrow[r] = 0.f; }

  __syncthreads();  // drains prologue stage (vmcnt 0)

  for (int t = 0; t < nt; ++t) {
    const int k0 = kbeg + t * 64;
    if (t + 1 < nt)
      stage_kv(kb_h, vt_h, k0 + 64, w, l, Ks[(t + 1) & 1], Vs[(t + 1) & 1]);
    if (k0 == q0)  // block-uniform branch: diagonal (masked) tile
      attn_tile<true>(k0, qrbase, lr, lg, qf, Ks[t & 1], Vs[t & 1], Ps[w], oacc, mrow, lrow);
    else
      attn_tile<false>(k0, qrbase, lr, lg, qf, Ks[t & 1], Vs[t & 1], Ps[w], oacc, mrow, lrow);
    __syncthreads();  // drains next-tile stage; releases buffers
  }

  // finalize l: cross-lane reduce over the 16 lanes sharing each row
#pragma unroll
  for (int r = 0; r < 4; ++r)
#pragma unroll
    for (int m = 8; m >= 1; m >>= 1) lrow[r] += __shfl_xor(lrow[r], m, 16);

  // epilogue: unnormalized partial O (bf16) + per-row m,l
  const size_t base = (((size_t)sp * 16 + h) * 32 + qt) * 64;
#pragma unroll
  for (int ni = 0; ni < 8; ++ni)
#pragma unroll
    for (int r = 0; r < 4; ++r)
      Op[(base + w * 16 + lg * 4 + r) * 128 + ni * 16 + lr] = f2b(oacc[ni][r]);
  if (lr == 0) {
#pragma unroll
    for (int r = 0; r < 4; ++r) {
      size_t mi = (base + w * 16 + lg * 4 + r) * 2;
      ml[mi] = mrow[r]; ml[mi + 1] = lrow[r];
    }
  }
}

// ---------- combine K-split partials (static indexing — rule #20) ----------
__global__ __launch_bounds__(256) void attn_combine(const unsigned short* __restrict__ Op,
                                                    const float* __restrict__ ml,
                                                    unsigned short* __restrict__ ob) {
  const int qt = blockIdx.x, h = blockIdx.y;
  const int q0 = qt * 64;
  const int ns = (qt >> 3) + 1;  // 1..4 valid splits
  const int t = threadIdx.x;
  const int row = t >> 2, dp = (t & 3) * 32;

  float m_s[4], l_s[4];
  float M = -1e30f;
#pragma unroll
  for (int s = 0; s < 4; ++s) {
    if (s < ns) {
      size_t mi = ((((size_t)s * 16 + h) * 32 + qt) * 64 + row) * 2;
      m_s[s] = ml[mi]; l_s[s] = ml[mi + 1];
    } else { m_s[s] = -1e30f; l_s[s] = 0.f; }
    M = fmaxf(M, m_s[s]);
  }
  float L = 0.f, wgt[4];
#pragma unroll
  for (int s = 0; s < 4; ++s) { wgt[s] = exp2f(m_s[s] - M); L += l_s[s] * wgt[s]; }
  float invL = 1.f / L;

  float acc[32];
#pragma unroll
  for (int jj = 0; jj < 32; ++jj) acc[jj] = 0.f;
#pragma unroll
  for (int s = 0; s < 4; ++s) {
    if (s < ns) {
      const unsigned short* op = Op + ((((size_t)s * 16 + h) * 32 + qt) * 64 + row) * 128 + dp;
      float wg = wgt[s] * invL;
#pragma unroll
      for (int jj = 0; jj < 32; jj += 8) {
        bf16x8 v = *reinterpret_cast<const bf16x8*>(op + jj);
#pragma unroll
        for (int e = 0; e < 8; ++e) acc[jj + e] += wg * b2f((unsigned short)v[e]);
      }
    }
  }
  unsigned short* o = ob + (size_t)(q0 + row) * 2048 + h * 128 + dp;
#pragma unroll
  for (int jj = 0; jj < 32; ++jj) o[jj] = f2b(acc[jj]);
}

// ---------- launch ----------
extern "C" void kernel_launch(void* const* d_in, const int* in_sizes, int n_in,
                              void* d_out, int out_size, void* d_ws, size_t ws_size,
                              hipStream_t stream) {
  const float* hs   = (const float*)d_in[0];
  const int*   pos  = (const int*)d_in[1];
  const float* wqkv = (const float*)d_in[2];
  const float* qnw  = (const float*)d_in[3];
  const float* knw  = (const float*)d_in[4];
  const float* wo   = (const float*)d_in[5];
  float* out = (float*)d_out;

  char* ws = (char*)d_ws;
  size_t off = 0;
  auto take = [&](size_t bytes) {
    char* p = ws + off;
    off = (off + bytes + 255) & ~(size_t)255;
    return p;
  };
  unsigned short* hidA  = (unsigned short*)take(2048ull * 2048 * 2);
  unsigned short* wqkvT = (unsigned short*)take(6144ull * 2048 * 2);
  unsigned short* woT   = (unsigned short*)take(2048ull * 2048 * 2);
  float*          qkvF  = (float*)take(2048ull * 6144 * 4);
  unsigned short* qbv   = (unsigned short*)take(2048ull * 2048 * 2);
  unsigned short* kbv   = (unsigned short*)take(2048ull * 2048 * 2);
  unsigned short* vtb   = (unsigned short*)take(2048ull * 2048 * 2);
  unsigned short* attnb = (unsigned short*)take(2048ull * 2048 * 2);
  // aliases over qkvF (dead after rms_rope + vtrans):
  // Opart: 4 splits * 16 heads * 32 qt * 64 rows * 128 d * 2B = 32 MiB
  unsigned short* Opart = (unsigned short*)qkvF;
  float*          mlb   = (float*)((char*)qkvF + 32ull * 1024 * 1024);  // 2 MiB, fits 48 MiB

  cast_f32_bf16<<<4096, 256, 0, stream>>>(hs, hidA, 1048576);
  tcast<<<dim3(192, 64), 256, 0, stream>>>(wqkv, wqkvT, 2048, 6144);
  tcast<<<dim3(64, 64), 256, 0, stream>>>(wo, woT, 2048, 2048);
  gemm_bt<<<dim3(48, 16), 256, 0, stream>>>(hidA, wqkvT, qkvF, 2048, 6144, 2048);
  rms_rope<<<2048, 256, 0, stream>>>(qkvF, pos, qnw, knw, qbv, kbv);
  vtrans<<<dim3(64, 64), 256, 0, stream>>>(qkvF, vtb);
  attn_part<<<dim3(32, 16, 4), 256, 0, stream>>>(qbv, kbv, vtb, Opart, mlb);
  attn_combine<<<dim3(32, 16), 256, 0, stream>>>(Opart, mlb, attnb);
  gemm_bt<<<dim3(16, 16), 256, 0, stream>>>(attnb, woT, out, 2048, 2048, 2048);
}

// Round 9
// 337.250 us; speedup vs baseline: 1.1111x; 1.1000x over previous
//
#include <hip/hip_runtime.h>
#include <hip/hip_bf16.h>

// ---------- types ----------
typedef __attribute__((ext_vector_type(8))) short bf16x8;   // 8 bf16 in 4 VGPRs
typedef __attribute__((ext_vector_type(4))) float f32x4;

__device__ inline unsigned short f2b(float x) {
  __hip_bfloat16 b = __float2bfloat16(x);
  return *reinterpret_cast<unsigned short*>(&b);
}
__device__ inline float b2f(unsigned short u) {
  return __bfloat162float(*reinterpret_cast<const __hip_bfloat16*>(&u));
}

#define GAS(p) ((const __attribute__((address_space(1))) void*)(p))
#define LAS(p) ((__attribute__((address_space(3))) void*)(p))

// ---------- elementwise cast f32 -> bf16 (vectorized) ----------
__global__ __launch_bounds__(256) void cast_f32_bf16(const float* __restrict__ X,
                                                     unsigned short* __restrict__ Y, int n4) {
  int i = blockIdx.x * 256 + threadIdx.x;
  if (i < n4) {
    float4 v = reinterpret_cast<const float4*>(X)[i];
    ushort4 o;
    o.x = f2b(v.x); o.y = f2b(v.y); o.z = f2b(v.z); o.w = f2b(v.w);
    reinterpret_cast<ushort4*>(Y)[i] = o;
  }
}

// ---------- transpose + cast: W [K][N] f32 -> Wt [N][K] bf16 ----------
__global__ __launch_bounds__(256) void tcast(const float* __restrict__ W,
                                             unsigned short* __restrict__ Wt, int K, int N) {
  __shared__ float tile[32][33];
  int n0 = blockIdx.x * 32, k0 = blockIdx.y * 32;
  int tx = threadIdx.x & 31, ty = threadIdx.x >> 5;  // 32 x 8
#pragma unroll
  for (int i = 0; i < 32; i += 8)
    tile[ty + i][tx] = W[(size_t)(k0 + ty + i) * N + n0 + tx];
  __syncthreads();
#pragma unroll
  for (int i = 0; i < 32; i += 8)
    Wt[(size_t)(n0 + ty + i) * K + k0 + tx] = f2b(tile[tx][ty + i]);
}

// ---------- V transpose+cast: qkvF[:,4096+c] f32 -> Vt[c][t] bf16 ----------
__global__ __launch_bounds__(256) void vtrans(const float* __restrict__ qkv,
                                              unsigned short* __restrict__ Vt) {
  __shared__ unsigned short tile[32][33];
  int c0 = blockIdx.x * 32;  // hd dim
  int t0 = blockIdx.y * 32;  // token dim
  int tx = threadIdx.x & 31, ty = threadIdx.x >> 5;  // 32 x 8
#pragma unroll
  for (int i = 0; i < 32; i += 8)
    tile[ty + i][tx] = f2b(qkv[(size_t)(t0 + ty + i) * 6144 + 4096 + c0 + tx]);
  __syncthreads();
#pragma unroll
  for (int i = 0; i < 32; i += 8)
    Vt[(size_t)(c0 + ty + i) * 2048 + t0 + tx] = tile[tx][ty + i];
}

// ---------- bf16 MFMA GEMM: C[M][N] = A[M][K] * Bt[N][K]^T, fp32 out ----------
// 128x128 tile, BK=32, 256 threads (4 waves, 2x2 wave grid, each wave 64x64).
__global__ __launch_bounds__(256) void gemm_bt(const unsigned short* __restrict__ A,
                                               const unsigned short* __restrict__ Bt,
                                               float* __restrict__ C, int M, int N, int K) {
  __shared__ unsigned short As[128 * 32];
  __shared__ unsigned short Bs[128 * 32];
  const int tid = threadIdx.x;
  const int w = tid >> 6, l = tid & 63;
  const int lr = l & 15, lg = l >> 4;
  const int wm = (w >> 1) << 6, wn = (w & 1) << 6;
  const size_t bm = (size_t)blockIdx.y * 128, bn = (size_t)blockIdx.x * 128;

  const int srow = tid >> 2;
  const int scol = (tid & 3) << 3;
  const unsigned short* Ag = A + (bm + srow) * (size_t)K + scol;
  const unsigned short* Bg = Bt + (bn + srow) * (size_t)K + scol;
  unsigned short* Al = As + w * 512;   // wave-uniform LDS base; HW adds lane*16B
  unsigned short* Bl = Bs + w * 512;

  f32x4 acc[4][4] = {};

  for (int k0 = 0; k0 < K; k0 += 32) {
    __syncthreads();
    __builtin_amdgcn_global_load_lds(GAS(Ag + k0), LAS(Al), 16, 0, 0);
    __builtin_amdgcn_global_load_lds(GAS(Ag + (size_t)64 * K + k0), LAS(Al + 2048), 16, 0, 0);
    __builtin_amdgcn_global_load_lds(GAS(Bg + k0), LAS(Bl), 16, 0, 0);
    __builtin_amdgcn_global_load_lds(GAS(Bg + (size_t)64 * K + k0), LAS(Bl + 2048), 16, 0, 0);
    __syncthreads();

    bf16x8 af[4], bfr[4];
#pragma unroll
    for (int mi = 0; mi < 4; ++mi)
      af[mi] = *reinterpret_cast<const bf16x8*>(&As[(wm + mi * 16 + lr) * 32 + lg * 8]);
#pragma unroll
    for (int ni = 0; ni < 4; ++ni)
      bfr[ni] = *reinterpret_cast<const bf16x8*>(&Bs[(wn + ni * 16 + lr) * 32 + lg * 8]);
#pragma unroll
    for (int mi = 0; mi < 4; ++mi)
#pragma unroll
      for (int ni = 0; ni < 4; ++ni)
        acc[mi][ni] = __builtin_amdgcn_mfma_f32_16x16x32_bf16(af[mi], bfr[ni], acc[mi][ni], 0, 0, 0);
  }

#pragma unroll
  for (int mi = 0; mi < 4; ++mi)
#pragma unroll
    for (int ni = 0; ni < 4; ++ni)
#pragma unroll
      for (int r = 0; r < 4; ++r) {
        size_t row = bm + wm + mi * 16 + lg * 4 + r;
        size_t col = bn + wn + ni * 16 + lr;
        C[row * N + col] = acc[mi][ni][r];
      }
}

// ---------- fused RMSNorm (over 2048) + RoPE, write bf16 q/k ----------
// Q is pre-scaled by softmax_scale * log2(e) so attention works in base-2.
__global__ __launch_bounds__(256) void rms_rope(const float* __restrict__ qkv,
                                                const int* __restrict__ pos,
                                                const float* __restrict__ qw,
                                                const float* __restrict__ kw,
                                                unsigned short* __restrict__ qb,
                                                unsigned short* __restrict__ kb) {
  const int t = blockIdx.x;
  const float* row = qkv + (size_t)t * 6144;
  __shared__ float redq[4], redk[4];
  __shared__ float cs[64], sn[64];
  const int tid = threadIdx.x, w = tid >> 6, l = tid & 63;

  float sq = 0.f, sk = 0.f;
#pragma unroll
  for (int i = 0; i < 8; ++i) {
    float a = row[tid + i * 256]; sq += a * a;
    float b = row[2048 + tid + i * 256]; sk += b * b;
  }
#pragma unroll
  for (int m = 32; m >= 1; m >>= 1) { sq += __shfl_xor(sq, m, 64); sk += __shfl_xor(sk, m, 64); }
  if (l == 0) { redq[w] = sq; redk[w] = sk; }
  if (tid < 64) {
    float fr = exp2f(-(float)tid * 0.31143075889569016f);  // theta^(-j/64)
    float ang = (float)pos[t] * fr;
    cs[tid] = cosf(ang);
    sn[tid] = sinf(ang);
  }
  __syncthreads();
  float rq = rsqrtf((redq[0] + redq[1] + redq[2] + redq[3]) * (1.f / 2048.f) + 1e-5f);
  float rk = rsqrtf((redk[0] + redk[1] + redk[2] + redk[3]) * (1.f / 2048.f) + 1e-5f);
  // fold softmax scale (1/sqrt(128)) * log2(e) into Q
  const float rqs = rq * 0.12753102543609887f;

  unsigned short* qo = qb + (size_t)t * 2048;
  unsigned short* ko = kb + (size_t)t * 2048;
#pragma unroll
  for (int pp = 0; pp < 4; ++pp) {
    int pr = tid + pp * 256;  // pair index 0..1023
    int h = pr >> 6, j = pr & 63;
    int b0 = h * 128 + j;
    float c = cs[j], s = sn[j];
    float x1 = row[b0] * rqs * qw[b0];
    float x2 = row[b0 + 64] * rqs * qw[b0 + 64];
    qo[b0]      = f2b(x1 * c - x2 * s);
    qo[b0 + 64] = f2b(x2 * c + x1 * s);
    float y1 = row[2048 + b0] * rk * kw[b0];
    float y2 = row[2048 + b0 + 64] * rk * kw[b0 + 64];
    ko[b0]      = f2b(y1 * c - y2 * s);
    ko[b0 + 64] = f2b(y2 * c + y1 * s);
  }
}

// ---------- attention helpers ----------
__device__ __forceinline__ void stage_kv(const unsigned short* __restrict__ kb_h,
                                         const unsigned short* __restrict__ vt_h,
                                         int k0, int w, int l,
                                         unsigned short* Ks, unsigned short* Vs) {
  // K: [64][128] swizzled 16B chunks (linear dest + inverse-swz source — rule #21)
  const int r0 = l >> 4, cph = l & 15;
#pragma unroll
  for (int rb = 0; rb < 16; rb += 4) {
    int row = w * 16 + rb + r0;
    int clog = (cph & 8) | ((cph & 7) ^ (row & 7));
    const unsigned short* src = kb_h + (size_t)(k0 + row) * 2048 + clog * 8;
    __builtin_amdgcn_global_load_lds(GAS(src), LAS((char*)Ks + (w * 16 + rb) * 256), 16, 0, 0);
  }
  // V^T: [128][64] swizzled 16B chunks
  const int r0v = l >> 3, cpv = l & 7;
#pragma unroll
  for (int rb = 0; rb < 32; rb += 8) {
    int row = w * 32 + rb + r0v;
    int clog = cpv ^ (row & 7);
    const unsigned short* src = vt_h + (size_t)row * 2048 + k0 + clog * 8;
    __builtin_amdgcn_global_load_lds(GAS(src), LAS((char*)Vs + (w * 32 + rb) * 128), 16, 0, 0);
  }
}

template <bool MASKED>
__device__ __forceinline__ void attn_tile(int k0, int qrbase, int lr, int lg,
                                          const bf16x8 (&qf)[4],
                                          const unsigned short* __restrict__ Ks,
                                          const unsigned short* __restrict__ Vs,
                                          unsigned short* __restrict__ PsW,
                                          f32x4 (&oacc)[8], float (&mrow)[4], float (&lrow)[4]) {
  f32x4 s[4] = {};
  __builtin_amdgcn_s_setprio(1);
#pragma unroll
  for (int kc = 0; kc < 4; ++kc)
#pragma unroll
    for (int cg = 0; cg < 4; ++cg) {
      int key = cg * 16 + lr;
      int c = 4 * kc + lg;
      int cswz = (c & 8) | ((c & 7) ^ (key & 7));
      bf16x8 kf = *reinterpret_cast<const bf16x8*>(&Ks[key * 128 + cswz * 8]);
      s[cg] = __builtin_amdgcn_mfma_f32_16x16x32_bf16(qf[kc], kf, s[cg], 0, 0, 0);
    }
  __builtin_amdgcn_s_setprio(0);

#pragma unroll
  for (int r = 0; r < 4; ++r) {
    const int qr = qrbase + lg * 4 + r;
    float p0 = s[0][r], p1 = s[1][r], p2 = s[2][r], p3 = s[3][r];
    if (MASKED) {
      if (k0 + lr > qr)      p0 = -1e30f;
      if (k0 + 16 + lr > qr) p1 = -1e30f;
      if (k0 + 32 + lr > qr) p2 = -1e30f;
      if (k0 + 48 + lr > qr) p3 = -1e30f;
    }
    float mx = fmaxf(fmaxf(p0, p1), fmaxf(p2, p3));
#pragma unroll
    for (int m = 8; m >= 1; m >>= 1) mx = fmaxf(mx, __shfl_xor(mx, m, 16));
    float mnew = fmaxf(mrow[r], mx);
    float corr = exp2f(mrow[r] - mnew);
    p0 = exp2f(p0 - mnew); p1 = exp2f(p1 - mnew);
    p2 = exp2f(p2 - mnew); p3 = exp2f(p3 - mnew);
    lrow[r] = lrow[r] * corr + ((p0 + p1) + (p2 + p3));  // per-lane partial; reduce at end
    mrow[r] = mnew;
#pragma unroll
    for (int ni = 0; ni < 8; ++ni) oacc[ni][r] *= corr;
    const int prow = (lg * 4 + r) * 72;
    PsW[prow + lr]      = f2b(p0);
    PsW[prow + 16 + lr] = f2b(p1);
    PsW[prow + 32 + lr] = f2b(p2);
    PsW[prow + 48 + lr] = f2b(p3);
  }

  __builtin_amdgcn_s_setprio(1);
#pragma unroll
  for (int ks = 0; ks < 2; ++ks) {
    bf16x8 pf = *reinterpret_cast<const bf16x8*>(&PsW[lr * 72 + ks * 32 + lg * 8]);
#pragma unroll
    for (int ni = 0; ni < 8; ++ni) {
      int d = ni * 16 + lr;
      int c = ks * 4 + lg;
      int cswz = c ^ (d & 7);
      bf16x8 vf = *reinterpret_cast<const bf16x8*>(&Vs[d * 64 + cswz * 8]);
      oacc[ni] = __builtin_amdgcn_mfma_f32_16x16x32_bf16(pf, vf, oacc[ni], 0, 0, 0);
    }
  }
  __builtin_amdgcn_s_setprio(0);
}

// ---------- causal flash attention, K-split partials, 2-phase pipelined ----------
// 1-D grid of 2048 blocks, XCD-aware swizzle (T1): assuming XCD = blockIdx%8,
// each XCD gets 2 fixed heads -> K/V working set 2 MB < 4 MB L2 per XCD.
// Within an XCD, longest blocks (high qt) dispatch first for tail packing.
// 256 thr (4 waves x 16 q-rows), KVBLK=64, double-buffered stage (2-phase).
__global__ __launch_bounds__(256) void attn_part(const unsigned short* __restrict__ qb,
                                                 const unsigned short* __restrict__ kb,
                                                 const unsigned short* __restrict__ vt,
                                                 unsigned short* __restrict__ Op,
                                                 float* __restrict__ ml) {
  __shared__ unsigned short Ks[2][64 * 128];
  __shared__ unsigned short Vs[2][128 * 64];
  __shared__ unsigned short Ps[4][16 * 72];
  // XCD-aware decode of (qt, h, sp) from linear block id
  const int p = blockIdx.x;
  const int xcd = p & 7;            // round-robin XCD assignment assumption
  const int i = p >> 3;             // 0..255 per XCD
  const int h = (xcd << 1) | (i & 1);  // 2 heads pinned per XCD
  const int j = i >> 1;             // 0..127
  const int qt = 31 - (j & 31);     // longest (most tiles) first
  const int sp = j >> 5;            // 0..3
  const int q0 = qt * 64;
  const int kbeg = sp * 512;
  if (kbeg >= q0 + 64) return;
  const int kend = min(kbeg + 512, q0 + 64);
  const int nt = (kend - kbeg) >> 6;  // 1..8 tiles
  const int tid = threadIdx.x, w = tid >> 6, l = tid & 63;
  const int lr = l & 15, lg = l >> 4;
  const int qrbase = q0 + w * 16;

  const unsigned short* kb_h = kb + h * 128;
  const unsigned short* vt_h = vt + (size_t)h * 128 * 2048;

  // prologue: stage tile 0, load Q while it flies
  stage_kv(kb_h, vt_h, kbeg, w, l, Ks[0], Vs[0]);

  bf16x8 qf[4];
  {
    const unsigned short* qp = qb + (size_t)(qrbase + lr) * 2048 + h * 128;
#pragma unroll
    for (int kc = 0; kc < 4; ++kc)
      qf[kc] = *reinterpret_cast<const bf16x8*>(qp + kc * 32 + lg * 8);
  }
  f32x4 oacc[8] = {};
  float mrow[4], lrow[4];
#pragma unroll
  for (int r = 0; r < 4; ++r) { mrow[r] = -1e30f; lrow[r] = 0.f; }

  __syncthreads();  // drains prologue stage (vmcnt 0)

  for (int t = 0; t < nt; ++t) {
    const int k0 = kbeg + t * 64;
    if (t + 1 < nt)
      stage_kv(kb_h, vt_h, k0 + 64, w, l, Ks[(t + 1) & 1], Vs[(t + 1) & 1]);
    if (k0 == q0)  // block-uniform branch: diagonal (masked) tile
      attn_tile<true>(k0, qrbase, lr, lg, qf, Ks[t & 1], Vs[t & 1], Ps[w], oacc, mrow, lrow);
    else
      attn_tile<false>(k0, qrbase, lr, lg, qf, Ks[t & 1], Vs[t & 1], Ps[w], oacc, mrow, lrow);
    __syncthreads();  // drains next-tile stage; releases buffers
  }

  // finalize l: cross-lane reduce over the 16 lanes sharing each row
#pragma unroll
  for (int r = 0; r < 4; ++r)
#pragma unroll
    for (int m = 8; m >= 1; m >>= 1) lrow[r] += __shfl_xor(lrow[r], m, 16);

  // epilogue: unnormalized partial O (bf16) + per-row m,l
  const size_t base = (((size_t)sp * 16 + h) * 32 + qt) * 64;
#pragma unroll
  for (int ni = 0; ni < 8; ++ni)
#pragma unroll
    for (int r = 0; r < 4; ++r)
      Op[(base + w * 16 + lg * 4 + r) * 128 + ni * 16 + lr] = f2b(oacc[ni][r]);
  if (lr == 0) {
#pragma unroll
    for (int r = 0; r < 4; ++r) {
      size_t mi = (base + w * 16 + lg * 4 + r) * 2;
      ml[mi] = mrow[r]; ml[mi + 1] = lrow[r];
    }
  }
}

// ---------- combine K-split partials (static indexing — rule #20) ----------
__global__ __launch_bounds__(256) void attn_combine(const unsigned short* __restrict__ Op,
                                                    const float* __restrict__ ml,
                                                    unsigned short* __restrict__ ob) {
  const int qt = blockIdx.x, h = blockIdx.y;
  const int q0 = qt * 64;
  const int ns = (qt >> 3) + 1;  // 1..4 valid splits
  const int t = threadIdx.x;
  const int row = t >> 2, dp = (t & 3) * 32;

  float m_s[4], l_s[4];
  float M = -1e30f;
#pragma unroll
  for (int s = 0; s < 4; ++s) {
    if (s < ns) {
      size_t mi = ((((size_t)s * 16 + h) * 32 + qt) * 64 + row) * 2;
      m_s[s] = ml[mi]; l_s[s] = ml[mi + 1];
    } else { m_s[s] = -1e30f; l_s[s] = 0.f; }
    M = fmaxf(M, m_s[s]);
  }
  float L = 0.f, wgt[4];
#pragma unroll
  for (int s = 0; s < 4; ++s) { wgt[s] = exp2f(m_s[s] - M); L += l_s[s] * wgt[s]; }
  float invL = 1.f / L;

  float acc[32];
#pragma unroll
  for (int jj = 0; jj < 32; ++jj) acc[jj] = 0.f;
#pragma unroll
  for (int s = 0; s < 4; ++s) {
    if (s < ns) {
      const unsigned short* op = Op + ((((size_t)s * 16 + h) * 32 + qt) * 64 + row) * 128 + dp;
      float wg = wgt[s] * invL;
#pragma unroll
      for (int jj = 0; jj < 32; jj += 8) {
        bf16x8 v = *reinterpret_cast<const bf16x8*>(op + jj);
#pragma unroll
        for (int e = 0; e < 8; ++e) acc[jj + e] += wg * b2f((unsigned short)v[e]);
      }
    }
  }
  unsigned short* o = ob + (size_t)(q0 + row) * 2048 + h * 128 + dp;
#pragma unroll
  for (int jj = 0; jj < 32; ++jj) o[jj] = f2b(acc[jj]);
}

// ---------- launch ----------
extern "C" void kernel_launch(void* const* d_in, const int* in_sizes, int n_in,
                              void* d_out, int out_size, void* d_ws, size_t ws_size,
                              hipStream_t stream) {
  const float* hs   = (const float*)d_in[0];
  const int*   pos  = (const int*)d_in[1];
  const float* wqkv = (const float*)d_in[2];
  const float* qnw  = (const float*)d_in[3];
  const float* knw  = (const float*)d_in[4];
  const float* wo   = (const float*)d_in[5];
  float* out = (float*)d_out;

  char* ws = (char*)d_ws;
  size_t off = 0;
  auto take = [&](size_t bytes) {
    char* p = ws + off;
    off = (off + bytes + 255) & ~(size_t)255;
    return p;
  };
  unsigned short* hidA  = (unsigned short*)take(2048ull * 2048 * 2);
  unsigned short* wqkvT = (unsigned short*)take(6144ull * 2048 * 2);
  unsigned short* woT   = (unsigned short*)take(2048ull * 2048 * 2);
  float*          qkvF  = (float*)take(2048ull * 6144 * 4);
  unsigned short* qbv   = (unsigned short*)take(2048ull * 2048 * 2);
  unsigned short* kbv   = (unsigned short*)take(2048ull * 2048 * 2);
  unsigned short* vtb   = (unsigned short*)take(2048ull * 2048 * 2);
  unsigned short* attnb = (unsigned short*)take(2048ull * 2048 * 2);
  // aliases over qkvF (dead after rms_rope + vtrans):
  // Opart: 4 splits * 16 heads * 32 qt * 64 rows * 128 d * 2B = 32 MiB
  unsigned short* Opart = (unsigned short*)qkvF;
  float*          mlb   = (float*)((char*)qkvF + 32ull * 1024 * 1024);  // 2 MiB, fits 48 MiB

  cast_f32_bf16<<<4096, 256, 0, stream>>>(hs, hidA, 1048576);
  tcast<<<dim3(192, 64), 256, 0, stream>>>(wqkv, wqkvT, 2048, 6144);
  tcast<<<dim3(64, 64), 256, 0, stream>>>(wo, woT, 2048, 2048);
  gemm_bt<<<dim3(48, 16), 256, 0, stream>>>(hidA, wqkvT, qkvF, 2048, 6144, 2048);
  rms_rope<<<2048, 256, 0, stream>>>(qkvF, pos, qnw, knw, qbv, kbv);
  vtrans<<<dim3(64, 64), 256, 0, stream>>>(qkvF, vtb);
  attn_part<<<dim3(2048), 256, 0, stream>>>(qbv, kbv, vtb, Opart, mlb);
  attn_combine<<<dim3(32, 16), 256, 0, stream>>>(Opart, mlb, attnb);
  gemm_bt<<<dim3(16, 16), 256, 0, stream>>>(attnb, woT, out, 2048, 2048, 2048);
}

// Round 10
// 325.895 us; speedup vs baseline: 1.1498x; 1.0348x over previous
//
#include <hip/hip_runtime.h>
#include <hip/hip_bf16.h>

// ---------- types ----------
typedef __attribute__((ext_vector_type(8))) short bf16x8;   // 8 bf16 in 4 VGPRs
typedef __attribute__((ext_vector_type(4))) float f32x4;

__device__ inline unsigned short f2b(float x) {
  __hip_bfloat16 b = __float2bfloat16(x);
  return *reinterpret_cast<unsigned short*>(&b);
}
__device__ inline float b2f(unsigned short u) {
  return __bfloat162float(*reinterpret_cast<const __hip_bfloat16*>(&u));
}

#define GAS(p) ((const __attribute__((address_space(1))) void*)(p))
#define LAS(p) ((__attribute__((address_space(3))) void*)(p))

// ---------- elementwise cast f32 -> bf16 (vectorized) ----------
__global__ __launch_bounds__(256) void cast_f32_bf16(const float* __restrict__ X,
                                                     unsigned short* __restrict__ Y, int n4) {
  int i = blockIdx.x * 256 + threadIdx.x;
  if (i < n4) {
    float4 v = reinterpret_cast<const float4*>(X)[i];
    ushort4 o;
    o.x = f2b(v.x); o.y = f2b(v.y); o.z = f2b(v.z); o.w = f2b(v.w);
    reinterpret_cast<ushort4*>(Y)[i] = o;
  }
}

// ---------- transpose + cast: W [K][N] f32 -> Wt [N][K] bf16 ----------
__global__ __launch_bounds__(256) void tcast(const float* __restrict__ W,
                                             unsigned short* __restrict__ Wt, int K, int N) {
  __shared__ float tile[32][33];
  int n0 = blockIdx.x * 32, k0 = blockIdx.y * 32;
  int tx = threadIdx.x & 31, ty = threadIdx.x >> 5;  // 32 x 8
#pragma unroll
  for (int i = 0; i < 32; i += 8)
    tile[ty + i][tx] = W[(size_t)(k0 + ty + i) * N + n0 + tx];
  __syncthreads();
#pragma unroll
  for (int i = 0; i < 32; i += 8)
    Wt[(size_t)(n0 + ty + i) * K + k0 + tx] = f2b(tile[tx][ty + i]);
}

// ---------- V transpose+cast: qkvF[:,4096+c] f32 -> Vt[c][t] bf16 ----------
__global__ __launch_bounds__(256) void vtrans(const float* __restrict__ qkv,
                                              unsigned short* __restrict__ Vt) {
  __shared__ unsigned short tile[32][33];
  int c0 = blockIdx.x * 32;  // hd dim
  int t0 = blockIdx.y * 32;  // token dim
  int tx = threadIdx.x & 31, ty = threadIdx.x >> 5;  // 32 x 8
#pragma unroll
  for (int i = 0; i < 32; i += 8)
    tile[ty + i][tx] = f2b(qkv[(size_t)(t0 + ty + i) * 6144 + 4096 + c0 + tx]);
  __syncthreads();
#pragma unroll
  for (int i = 0; i < 32; i += 8)
    Vt[(size_t)(c0 + ty + i) * 2048 + t0 + tx] = tile[tx][ty + i];
}

// ---------- bf16 MFMA GEMM (128x128, m97-style) — kept for out-projection ----------
__global__ __launch_bounds__(256) void gemm_bt(const unsigned short* __restrict__ A,
                                               const unsigned short* __restrict__ Bt,
                                               float* __restrict__ C, int M, int N, int K) {
  __shared__ unsigned short As[128 * 32];
  __shared__ unsigned short Bs[128 * 32];
  const int tid = threadIdx.x;
  const int w = tid >> 6, l = tid & 63;
  const int lr = l & 15, lg = l >> 4;
  const int wm = (w >> 1) << 6, wn = (w & 1) << 6;
  const size_t bm = (size_t)blockIdx.y * 128, bn = (size_t)blockIdx.x * 128;

  const int srow = tid >> 2;
  const int scol = (tid & 3) << 3;
  const unsigned short* Ag = A + (bm + srow) * (size_t)K + scol;
  const unsigned short* Bg = Bt + (bn + srow) * (size_t)K + scol;
  unsigned short* Al = As + w * 512;
  unsigned short* Bl = Bs + w * 512;

  f32x4 acc[4][4] = {};

  for (int k0 = 0; k0 < K; k0 += 32) {
    __syncthreads();
    __builtin_amdgcn_global_load_lds(GAS(Ag + k0), LAS(Al), 16, 0, 0);
    __builtin_amdgcn_global_load_lds(GAS(Ag + (size_t)64 * K + k0), LAS(Al + 2048), 16, 0, 0);
    __builtin_amdgcn_global_load_lds(GAS(Bg + k0), LAS(Bl), 16, 0, 0);
    __builtin_amdgcn_global_load_lds(GAS(Bg + (size_t)64 * K + k0), LAS(Bl + 2048), 16, 0, 0);
    __syncthreads();

    bf16x8 af[4], bfr[4];
#pragma unroll
    for (int mi = 0; mi < 4; ++mi)
      af[mi] = *reinterpret_cast<const bf16x8*>(&As[(wm + mi * 16 + lr) * 32 + lg * 8]);
#pragma unroll
    for (int ni = 0; ni < 4; ++ni)
      bfr[ni] = *reinterpret_cast<const bf16x8*>(&Bs[(wn + ni * 16 + lr) * 32 + lg * 8]);
#pragma unroll
    for (int mi = 0; mi < 4; ++mi)
#pragma unroll
      for (int ni = 0; ni < 4; ++ni)
        acc[mi][ni] = __builtin_amdgcn_mfma_f32_16x16x32_bf16(af[mi], bfr[ni], acc[mi][ni], 0, 0, 0);
  }

#pragma unroll
  for (int mi = 0; mi < 4; ++mi)
#pragma unroll
    for (int ni = 0; ni < 4; ++ni)
#pragma unroll
      for (int r = 0; r < 4; ++r) {
        size_t row = bm + wm + mi * 16 + lg * 4 + r;
        size_t col = bn + wn + ni * 16 + lr;
        C[row * N + col] = acc[mi][ni][r];
      }
}

// ---------- 256x256 8-wave pipelined GEMM (counted-vmcnt, swizzled LDS) ----------
// C[M][N] = A[M][K] * Bt[N][K]^T. 512 thr = 8 waves (2M x 4N), per-wave 128x64.
// BK=32. LDS: 3 tile-buffers x (A 16KB + B 16KB) = 96 KB dynamic.
// Tile layout [128][64] bf16: tile-row tr at LDS row tr>>1, half h=tr&1;
// 16B chunk p = (h*4 + q) ^ (r&7)  (q = k/8) -> 2-way-max bank aliasing (free).
// Staged via global_load_lds (linear dest, inverse-swizzled per-lane source).
// Pipeline: depth-2 prefetch; per iter: vmcnt(4) [never 0] -> s_barrier ->
// stage(t+2) -> ds_read(t) -> setprio(1) 32 MFMA setprio(0).
__global__ __launch_bounds__(512, 2) void gemm256(const unsigned short* __restrict__ A,
                                                  const unsigned short* __restrict__ Bt,
                                                  float* __restrict__ C, int M, int N, int K) {
  extern __shared__ unsigned short lds[];  // [3][A:8192 | B:8192] elems
  const int tid = threadIdx.x, w = tid >> 6, l = tid & 63;
  const int lr = l & 15, lg = (l >> 4) & 3;
  const int wm = (w >> 2) * 128, wn = (w & 3) * 64;
  const size_t bm = (size_t)blockIdx.y * 256, bn = (size_t)blockIdx.x * 256;
  const int nt = K >> 5;

  // per-lane inverse-swizzled global source offsets for staging (rule #21)
  const int sr = w * 8 + (l >> 3);          // LDS row within 64-row half-call
  const int sc = (l & 7) ^ (sr & 7);        // logical chunk for this physical slot
  const int sh = sc >> 2, sq = sc & 3;

  auto stage = [&](int t) {
    const int b = t % 3;
    unsigned short* Ab = lds + (size_t)b * 16384;
    unsigned short* Bb = Ab + 8192;
    const int k0 = t * 32;
#pragma unroll
    for (int cc = 0; cc < 2; ++cc) {
      const int r = cc * 64 + sr;
      const int ccf = (cc * 64) & 0;  // (sr swizzle is row-local; cc*64 keeps r&7 == sr&7)
      (void)ccf;
      const unsigned short* sa = A + (bm + 2 * r + sh) * (size_t)K + k0 + sq * 8;
      __builtin_amdgcn_global_load_lds(GAS(sa), LAS(Ab + (cc * 64 + w * 8) * 64), 16, 0, 0);
      const unsigned short* sb = Bt + (bn + 2 * r + sh) * (size_t)K + k0 + sq * 8;
      __builtin_amdgcn_global_load_lds(GAS(sb), LAS(Bb + (cc * 64 + w * 8) * 64), 16, 0, 0);
    }
  };

  f32x4 acc[8][4] = {};

  stage(0);
  stage(1);

  for (int t = 0; t < nt; ++t) {
    if (t == nt - 1) asm volatile("s_waitcnt vmcnt(0)" ::: "memory");
    else             asm volatile("s_waitcnt vmcnt(4)" ::: "memory");
    __builtin_amdgcn_s_barrier();
    if (t + 2 < nt) stage(t + 2);

    const int b = t % 3;
    const unsigned short* Ab = lds + (size_t)b * 16384;
    const unsigned short* Bb = Ab + 8192;

    bf16x8 af[8], bg[4];
#pragma unroll
    for (int mi = 0; mi < 8; ++mi) {
      const int tr = wm + mi * 16 + lr;
      const int r = tr >> 1;
      const int p = (((tr & 1) << 2) + lg) ^ (r & 7);
      af[mi] = *reinterpret_cast<const bf16x8*>(Ab + r * 64 + p * 8);
    }
#pragma unroll
    for (int ni = 0; ni < 4; ++ni) {
      const int tc = wn + ni * 16 + lr;
      const int r = tc >> 1;
      const int p = (((tc & 1) << 2) + lg) ^ (r & 7);
      bg[ni] = *reinterpret_cast<const bf16x8*>(Bb + r * 64 + p * 8);
    }

    __builtin_amdgcn_s_setprio(1);
#pragma unroll
    for (int mi = 0; mi < 8; ++mi)
#pragma unroll
      for (int ni = 0; ni < 4; ++ni)
        acc[mi][ni] = __builtin_amdgcn_mfma_f32_16x16x32_bf16(af[mi], bg[ni], acc[mi][ni], 0, 0, 0);
    __builtin_amdgcn_s_setprio(0);
  }

#pragma unroll
  for (int mi = 0; mi < 8; ++mi)
#pragma unroll
    for (int ni = 0; ni < 4; ++ni)
#pragma unroll
      for (int r = 0; r < 4; ++r) {
        size_t row = bm + wm + mi * 16 + lg * 4 + r;
        size_t col = bn + wn + ni * 16 + lr;
        C[row * N + col] = acc[mi][ni][r];
      }
}

// ---------- fused RMSNorm (over 2048) + RoPE, write bf16 q/k ----------
// Q is pre-scaled by softmax_scale * log2(e) so attention works in base-2.
__global__ __launch_bounds__(256) void rms_rope(const float* __restrict__ qkv,
                                                const int* __restrict__ pos,
                                                const float* __restrict__ qw,
                                                const float* __restrict__ kw,
                                                unsigned short* __restrict__ qb,
                                                unsigned short* __restrict__ kb) {
  const int t = blockIdx.x;
  const float* row = qkv + (size_t)t * 6144;
  __shared__ float redq[4], redk[4];
  __shared__ float cs[64], sn[64];
  const int tid = threadIdx.x, w = tid >> 6, l = tid & 63;

  float sq = 0.f, sk = 0.f;
#pragma unroll
  for (int i = 0; i < 8; ++i) {
    float a = row[tid + i * 256]; sq += a * a;
    float b = row[2048 + tid + i * 256]; sk += b * b;
  }
#pragma unroll
  for (int m = 32; m >= 1; m >>= 1) { sq += __shfl_xor(sq, m, 64); sk += __shfl_xor(sk, m, 64); }
  if (l == 0) { redq[w] = sq; redk[w] = sk; }
  if (tid < 64) {
    float fr = exp2f(-(float)tid * 0.31143075889569016f);  // theta^(-j/64)
    float ang = (float)pos[t] * fr;
    cs[tid] = cosf(ang);
    sn[tid] = sinf(ang);
  }
  __syncthreads();
  float rq = rsqrtf((redq[0] + redq[1] + redq[2] + redq[3]) * (1.f / 2048.f) + 1e-5f);
  float rk = rsqrtf((redk[0] + redk[1] + redk[2] + redk[3]) * (1.f / 2048.f) + 1e-5f);
  // fold softmax scale (1/sqrt(128)) * log2(e) into Q
  const float rqs = rq * 0.12753102543609887f;

  unsigned short* qo = qb + (size_t)t * 2048;
  unsigned short* ko = kb + (size_t)t * 2048;
#pragma unroll
  for (int pp = 0; pp < 4; ++pp) {
    int pr = tid + pp * 256;  // pair index 0..1023
    int h = pr >> 6, j = pr & 63;
    int b0 = h * 128 + j;
    float c = cs[j], s = sn[j];
    float x1 = row[b0] * rqs * qw[b0];
    float x2 = row[b0 + 64] * rqs * qw[b0 + 64];
    qo[b0]      = f2b(x1 * c - x2 * s);
    qo[b0 + 64] = f2b(x2 * c + x1 * s);
    float y1 = row[2048 + b0] * rk * kw[b0];
    float y2 = row[2048 + b0 + 64] * rk * kw[b0 + 64];
    ko[b0]      = f2b(y1 * c - y2 * s);
    ko[b0 + 64] = f2b(y2 * c + y1 * s);
  }
}

// ---------- attention helpers ----------
__device__ __forceinline__ void stage_kv(const unsigned short* __restrict__ kb_h,
                                         const unsigned short* __restrict__ vt_h,
                                         int k0, int w, int l,
                                         unsigned short* Ks, unsigned short* Vs) {
  // K: [64][128] swizzled 16B chunks (linear dest + inverse-swz source — rule #21)
  const int r0 = l >> 4, cph = l & 15;
#pragma unroll
  for (int rb = 0; rb < 16; rb += 4) {
    int row = w * 16 + rb + r0;
    int clog = (cph & 8) | ((cph & 7) ^ (row & 7));
    const unsigned short* src = kb_h + (size_t)(k0 + row) * 2048 + clog * 8;
    __builtin_amdgcn_global_load_lds(GAS(src), LAS((char*)Ks + (w * 16 + rb) * 256), 16, 0, 0);
  }
  // V^T: [128][64] swizzled 16B chunks
  const int r0v = l >> 3, cpv = l & 7;
#pragma unroll
  for (int rb = 0; rb < 32; rb += 8) {
    int row = w * 32 + rb + r0v;
    int clog = cpv ^ (row & 7);
    const unsigned short* src = vt_h + (size_t)row * 2048 + k0 + clog * 8;
    __builtin_amdgcn_global_load_lds(GAS(src), LAS((char*)Vs + (w * 32 + rb) * 128), 16, 0, 0);
  }
}

template <bool MASKED>
__device__ __forceinline__ void attn_tile(int k0, int qrbase, int lr, int lg,
                                          const bf16x8 (&qf)[4],
                                          const unsigned short* __restrict__ Ks,
                                          const unsigned short* __restrict__ Vs,
                                          unsigned short* __restrict__ PsW,
                                          f32x4 (&oacc)[8], float (&mrow)[4], float (&lrow)[4]) {
  f32x4 s[4] = {};
  __builtin_amdgcn_s_setprio(1);
#pragma unroll
  for (int kc = 0; kc < 4; ++kc)
#pragma unroll
    for (int cg = 0; cg < 4; ++cg) {
      int key = cg * 16 + lr;
      int c = 4 * kc + lg;
      int cswz = (c & 8) | ((c & 7) ^ (key & 7));
      bf16x8 kf = *reinterpret_cast<const bf16x8*>(&Ks[key * 128 + cswz * 8]);
      s[cg] = __builtin_amdgcn_mfma_f32_16x16x32_bf16(qf[kc], kf, s[cg], 0, 0, 0);
    }
  __builtin_amdgcn_s_setprio(0);

#pragma unroll
  for (int r = 0; r < 4; ++r) {
    const int qr = qrbase + lg * 4 + r;
    float p0 = s[0][r], p1 = s[1][r], p2 = s[2][r], p3 = s[3][r];
    if (MASKED) {
      if (k0 + lr > qr)      p0 = -1e30f;
      if (k0 + 16 + lr > qr) p1 = -1e30f;
      if (k0 + 32 + lr > qr) p2 = -1e30f;
      if (k0 + 48 + lr > qr) p3 = -1e30f;
    }
    float mx = fmaxf(fmaxf(p0, p1), fmaxf(p2, p3));
#pragma unroll
    for (int m = 8; m >= 1; m >>= 1) mx = fmaxf(mx, __shfl_xor(mx, m, 16));
    float mnew = fmaxf(mrow[r], mx);
    float corr = exp2f(mrow[r] - mnew);
    p0 = exp2f(p0 - mnew); p1 = exp2f(p1 - mnew);
    p2 = exp2f(p2 - mnew); p3 = exp2f(p3 - mnew);
    lrow[r] = lrow[r] * corr + ((p0 + p1) + (p2 + p3));  // per-lane partial; reduce at end
    mrow[r] = mnew;
#pragma unroll
    for (int ni = 0; ni < 8; ++ni) oacc[ni][r] *= corr;
    const int prow = (lg * 4 + r) * 72;
    PsW[prow + lr]      = f2b(p0);
    PsW[prow + 16 + lr] = f2b(p1);
    PsW[prow + 32 + lr] = f2b(p2);
    PsW[prow + 48 + lr] = f2b(p3);
  }

  __builtin_amdgcn_s_setprio(1);
#pragma unroll
  for (int ks = 0; ks < 2; ++ks) {
    bf16x8 pf = *reinterpret_cast<const bf16x8*>(&PsW[lr * 72 + ks * 32 + lg * 8]);
#pragma unroll
    for (int ni = 0; ni < 8; ++ni) {
      int d = ni * 16 + lr;
      int c = ks * 4 + lg;
      int cswz = c ^ (d & 7);
      bf16x8 vf = *reinterpret_cast<const bf16x8*>(&Vs[d * 64 + cswz * 8]);
      oacc[ni] = __builtin_amdgcn_mfma_f32_16x16x32_bf16(pf, vf, oacc[ni], 0, 0, 0);
    }
  }
  __builtin_amdgcn_s_setprio(0);
}

// ---------- causal flash attention, K-split partials, 2-phase pipelined ----------
// 1-D grid of 2048 blocks, XCD-aware swizzle (T1): assuming XCD = blockIdx%8,
// each XCD gets 2 fixed heads -> K/V working set 2 MB < 4 MB L2 per XCD.
__global__ __launch_bounds__(256) void attn_part(const unsigned short* __restrict__ qb,
                                                 const unsigned short* __restrict__ kb,
                                                 const unsigned short* __restrict__ vt,
                                                 unsigned short* __restrict__ Op,
                                                 float* __restrict__ ml) {
  __shared__ unsigned short Ks[2][64 * 128];
  __shared__ unsigned short Vs[2][128 * 64];
  __shared__ unsigned short Ps[4][16 * 72];
  // XCD-aware decode of (qt, h, sp) from linear block id
  const int p = blockIdx.x;
  const int xcd = p & 7;            // round-robin XCD assignment assumption
  const int i = p >> 3;             // 0..255 per XCD
  const int h = (xcd << 1) | (i & 1);  // 2 heads pinned per XCD
  const int j = i >> 1;             // 0..127
  const int qt = 31 - (j & 31);     // longest (most tiles) first
  const int sp = j >> 5;            // 0..3
  const int q0 = qt * 64;
  const int kbeg = sp * 512;
  if (kbeg >= q0 + 64) return;
  const int kend = min(kbeg + 512, q0 + 64);
  const int nt = (kend - kbeg) >> 6;  // 1..8 tiles
  const int tid = threadIdx.x, w = tid >> 6, l = tid & 63;
  const int lr = l & 15, lg = l >> 4;
  const int qrbase = q0 + w * 16;

  const unsigned short* kb_h = kb + h * 128;
  const unsigned short* vt_h = vt + (size_t)h * 128 * 2048;

  // prologue: stage tile 0, load Q while it flies
  stage_kv(kb_h, vt_h, kbeg, w, l, Ks[0], Vs[0]);

  bf16x8 qf[4];
  {
    const unsigned short* qp = qb + (size_t)(qrbase + lr) * 2048 + h * 128;
#pragma unroll
    for (int kc = 0; kc < 4; ++kc)
      qf[kc] = *reinterpret_cast<const bf16x8*>(qp + kc * 32 + lg * 8);
  }
  f32x4 oacc[8] = {};
  float mrow[4], lrow[4];
#pragma unroll
  for (int r = 0; r < 4; ++r) { mrow[r] = -1e30f; lrow[r] = 0.f; }

  __syncthreads();  // drains prologue stage (vmcnt 0)

  for (int t = 0; t < nt; ++t) {
    const int k0 = kbeg + t * 64;
    if (t + 1 < nt)
      stage_kv(kb_h, vt_h, k0 + 64, w, l, Ks[(t + 1) & 1], Vs[(t + 1) & 1]);
    if (k0 == q0)  // block-uniform branch: diagonal (masked) tile
      attn_tile<true>(k0, qrbase, lr, lg, qf, Ks[t & 1], Vs[t & 1], Ps[w], oacc, mrow, lrow);
    else
      attn_tile<false>(k0, qrbase, lr, lg, qf, Ks[t & 1], Vs[t & 1], Ps[w], oacc, mrow, lrow);
    __syncthreads();  // drains next-tile stage; releases buffers
  }

  // finalize l: cross-lane reduce over the 16 lanes sharing each row
#pragma unroll
  for (int r = 0; r < 4; ++r)
#pragma unroll
    for (int m = 8; m >= 1; m >>= 1) lrow[r] += __shfl_xor(lrow[r], m, 16);

  // epilogue: unnormalized partial O (bf16) + per-row m,l
  const size_t base = (((size_t)sp * 16 + h) * 32 + qt) * 64;
#pragma unroll
  for (int ni = 0; ni < 8; ++ni)
#pragma unroll
    for (int r = 0; r < 4; ++r)
      Op[(base + w * 16 + lg * 4 + r) * 128 + ni * 16 + lr] = f2b(oacc[ni][r]);
  if (lr == 0) {
#pragma unroll
    for (int r = 0; r < 4; ++r) {
      size_t mi = (base + w * 16 + lg * 4 + r) * 2;
      ml[mi] = mrow[r]; ml[mi + 1] = lrow[r];
    }
  }
}

// ---------- combine K-split partials (static indexing — rule #20) ----------
__global__ __launch_bounds__(256) void attn_combine(const unsigned short* __restrict__ Op,
                                                    const float* __restrict__ ml,
                                                    unsigned short* __restrict__ ob) {
  const int qt = blockIdx.x, h = blockIdx.y;
  const int q0 = qt * 64;
  const int ns = (qt >> 3) + 1;  // 1..4 valid splits
  const int t = threadIdx.x;
  const int row = t >> 2, dp = (t & 3) * 32;

  float m_s[4], l_s[4];
  float M = -1e30f;
#pragma unroll
  for (int s = 0; s < 4; ++s) {
    if (s < ns) {
      size_t mi = ((((size_t)s * 16 + h) * 32 + qt) * 64 + row) * 2;
      m_s[s] = ml[mi]; l_s[s] = ml[mi + 1];
    } else { m_s[s] = -1e30f; l_s[s] = 0.f; }
    M = fmaxf(M, m_s[s]);
  }
  float L = 0.f, wgt[4];
#pragma unroll
  for (int s = 0; s < 4; ++s) { wgt[s] = exp2f(m_s[s] - M); L += l_s[s] * wgt[s]; }
  float invL = 1.f / L;

  float acc[32];
#pragma unroll
  for (int jj = 0; jj < 32; ++jj) acc[jj] = 0.f;
#pragma unroll
  for (int s = 0; s < 4; ++s) {
    if (s < ns) {
      const unsigned short* op = Op + ((((size_t)s * 16 + h) * 32 + qt) * 64 + row) * 128 + dp;
      float wg = wgt[s] * invL;
#pragma unroll
      for (int jj = 0; jj < 32; jj += 8) {
        bf16x8 v = *reinterpret_cast<const bf16x8*>(op + jj);
#pragma unroll
        for (int e = 0; e < 8; ++e) acc[jj + e] += wg * b2f((unsigned short)v[e]);
      }
    }
  }
  unsigned short* o = ob + (size_t)(q0 + row) * 2048 + h * 128 + dp;
#pragma unroll
  for (int jj = 0; jj < 32; ++jj) o[jj] = f2b(acc[jj]);
}

// ---------- launch ----------
extern "C" void kernel_launch(void* const* d_in, const int* in_sizes, int n_in,
                              void* d_out, int out_size, void* d_ws, size_t ws_size,
                              hipStream_t stream) {
  const float* hs   = (const float*)d_in[0];
  const int*   pos  = (const int*)d_in[1];
  const float* wqkv = (const float*)d_in[2];
  const float* qnw  = (const float*)d_in[3];
  const float* knw  = (const float*)d_in[4];
  const float* wo   = (const float*)d_in[5];
  float* out = (float*)d_out;

  char* ws = (char*)d_ws;
  size_t off = 0;
  auto take = [&](size_t bytes) {
    char* p = ws + off;
    off = (off + bytes + 255) & ~(size_t)255;
    return p;
  };
  unsigned short* hidA  = (unsigned short*)take(2048ull * 2048 * 2);
  unsigned short* wqkvT = (unsigned short*)take(6144ull * 2048 * 2);
  unsigned short* woT   = (unsigned short*)take(2048ull * 2048 * 2);
  float*          qkvF  = (float*)take(2048ull * 6144 * 4);
  unsigned short* qbv   = (unsigned short*)take(2048ull * 2048 * 2);
  unsigned short* kbv   = (unsigned short*)take(2048ull * 2048 * 2);
  unsigned short* vtb   = (unsigned short*)take(2048ull * 2048 * 2);
  unsigned short* attnb = (unsigned short*)take(2048ull * 2048 * 2);
  // aliases over qkvF (dead after rms_rope + vtrans):
  unsigned short* Opart = (unsigned short*)qkvF;
  float*          mlb   = (float*)((char*)qkvF + 32ull * 1024 * 1024);

  // allow 96 KB dynamic LDS for gemm256 (idempotent; host-side, capture-safe)
  hipFuncSetAttribute((const void*)gemm256, hipFuncAttributeMaxDynamicSharedMemorySize, 98304);

  cast_f32_bf16<<<4096, 256, 0, stream>>>(hs, hidA, 1048576);
  tcast<<<dim3(192, 64), 256, 0, stream>>>(wqkv, wqkvT, 2048, 6144);
  tcast<<<dim3(64, 64), 256, 0, stream>>>(wo, woT, 2048, 2048);
  gemm256<<<dim3(24, 8), 512, 98304, stream>>>(hidA, wqkvT, qkvF, 2048, 6144, 2048);
  rms_rope<<<2048, 256, 0, stream>>>(qkvF, pos, qnw, knw, qbv, kbv);
  vtrans<<<dim3(64, 64), 256, 0, stream>>>(qkvF, vtb);
  attn_part<<<dim3(2048), 256, 0, stream>>>(qbv, kbv, vtb, Opart, mlb);
  attn_combine<<<dim3(32, 16), 256, 0, stream>>>(Opart, mlb, attnb);
  gemm_bt<<<dim3(16, 16), 256, 0, stream>>>(attnb, woT, out, 2048, 2048, 2048);
}